// Round 9
// baseline (1150.598 us; speedup 1.0000x reference)
//
#include <hip/hip_runtime.h>

// ---------------------------------------------------------------------------
// MQA: out = softmax((X Wq)(X Wk)^T / 32)(X Wv) Wo, MQA broadcast K/V.
// B=2, S=2048, IN=HID=1024, H=16, D=64.
// Round 9: gemm64 software-pipelined (single change vs R8).
//   R8 accounting: proj+out_proj ~150us vs ~25us issue-rate model ->
//   latency-bound (barrier + exposed vmcnt per iter). Now: double-buffered
//   LDS, ONE barrier/iter, loads for it+1 issued right after stores of it
//   (vmcnt wait lands one full iteration later). Bit-identical arithmetic.
// Attention (32x32 S^T version, R8-verified) unchanged.
// ---------------------------------------------------------------------------

typedef unsigned int   u32;
typedef unsigned short u16;
typedef union { float4 v; float f[4]; } f4u;
typedef __attribute__((ext_vector_type(8)))  short frag16;  // 8 bf16 (4 VGPR)
typedef __attribute__((ext_vector_type(4)))  float f32x4;
typedef __attribute__((ext_vector_type(16))) float f32x16;  // 32x32 MFMA acc
typedef union { frag16 v; u16 e[8]; } bf8u;

static __device__ __forceinline__ u16 f2bf(float x) {
  union { float f; u32 u; } v; v.f = x;
  u32 r = v.u + 0x7fff + ((v.u >> 16) & 1);   // RNE
  return (u16)(r >> 16);
}

// ---------------------------------------------------------------------------
// 64x64 transpose+convert tile (prep_w helper).
// ---------------------------------------------------------------------------
static __device__ void tcvt_tile(const float* __restrict__ src,
                                 u16* __restrict__ dst,
                                 int C, int ldT, int rt, int ct,
                                 float (*t)[65]) {
  const int r0 = rt * 64, c0 = ct * 64;
  const int tr  = threadIdx.x >> 4;
  const int tc4 = (threadIdx.x & 15) * 4;
#pragma unroll
  for (int i = 0; i < 4; ++i) {
    f4u v; v.v = *(const float4*)(src + (size_t)(r0 + tr + i * 16) * C + c0 + tc4);
    t[tr + i * 16][tc4 + 0] = v.f[0];
    t[tr + i * 16][tc4 + 1] = v.f[1];
    t[tr + i * 16][tc4 + 2] = v.f[2];
    t[tr + i * 16][tc4 + 3] = v.f[3];
  }
  __syncthreads();
#pragma unroll
  for (int i = 0; i < 4; ++i) {
    const int oc = tr + i * 16;
    ushort4 o;
    o.x = f2bf(t[tc4 + 0][oc]);
    o.y = f2bf(t[tc4 + 1][oc]);
    o.z = f2bf(t[tc4 + 2][oc]);
    o.w = f2bf(t[tc4 + 3][oc]);
    *(ushort4*)(dst + (size_t)(c0 + oc) * ldT + r0 + tc4) = o;
  }
}

__global__ __launch_bounds__(256)
void prep_w(const float* __restrict__ Wq, const float* __restrict__ Wo,
            const float* __restrict__ Wk, const float* __restrict__ Wv,
            u16* __restrict__ wq_t, u16* __restrict__ wo_t,
            u16* __restrict__ wk_t, u16* __restrict__ wv_t) {
  __shared__ float t[64][65];
  const int bid = blockIdx.x;
  if (bid < 256)      tcvt_tile(Wq, wq_t, 1024, 1024, bid >> 4, bid & 15, t);
  else if (bid < 512) tcvt_tile(Wo, wo_t, 1024, 1024, (bid - 256) >> 4, (bid - 256) & 15, t);
  else if (bid < 528) tcvt_tile(Wk, wk_t, 64, 1024, bid - 512, 0, t);
  else                tcvt_tile(Wv, wv_t, 64, 1024, bid - 528, 0, t);
}

// ---------------------------------------------------------------------------
// 64x64-tile bf16 MFMA GEMM device fn — PIPELINED.
// BK=64, NIT=K/64. Double-buffered LDS, one barrier/iter:
//   it: store regs[cur] -> buf[cur]; issue loads(it+1) -> regs[cur^1];
//       __syncthreads(); MFMA from buf[cur].
// Safety: reads of buf[p] at iter it retire before that wave's store(it+1)
// (MFMA data dependency), which precedes barrier(it+1) < any store(it+2)
// to buf[p]. One barrier suffices.
// ---------------------------------------------------------------------------
#define GP 72
#define TSZ (64 * GP)
template <bool A_FP32>
static __device__ void gemm64(const float* __restrict__ Af32,
                              const u16* __restrict__ Abf,
                              const u16* __restrict__ Bt,
                              const float* __restrict__ bias,
                              void* __restrict__ Cout, int out_mode,
                              int row0, int col0, int N, int K, int ldT,
                              u16* As, u16* Bs) {   // each [2*TSZ]
  const int tid  = threadIdx.x;
  const int lane = tid & 63;
  const int quad = lane >> 4, l15 = lane & 15;
  const int w = tid >> 6, wy = w >> 1, wx = w & 1;

  f32x4 acc[2][2];
#pragma unroll
  for (int i = 0; i < 2; ++i)
#pragma unroll
    for (int j = 0; j < 2; ++j) {
      acc[i][j][0] = 0.f; acc[i][j][1] = 0.f;
      acc[i][j][2] = 0.f; acc[i][j][3] = 0.f;
    }

  const int r = tid >> 2, c16 = (tid & 3) * 16;
  const float* apf = Af32 ? (Af32 + (size_t)(row0 + r) * K + c16) : nullptr;
  const u16*   apb = Abf  ? (Abf  + (size_t)(row0 + r) * K + c16) : nullptr;
  const u16*   bp  = Bt + (size_t)(col0 + r) * K + c16;

  f4u    xa[2][4];   // fp32-A pipeline regs
  frag16 ra[2][2];   // bf16-A pipeline regs
  frag16 rb[2][2];   // B pipeline regs

  auto LOAD = [&](int set, int k0) {
    if (A_FP32) {
      xa[set][0].v = *(const float4*)(apf + k0);
      xa[set][1].v = *(const float4*)(apf + k0 + 4);
      xa[set][2].v = *(const float4*)(apf + k0 + 8);
      xa[set][3].v = *(const float4*)(apf + k0 + 12);
    } else {
      ra[set][0] = *(const frag16*)(apb + k0);
      ra[set][1] = *(const frag16*)(apb + k0 + 8);
    }
    rb[set][0] = *(const frag16*)(bp + k0);
    rb[set][1] = *(const frag16*)(bp + k0 + 8);
  };

  const int NIT = K >> 6;
  LOAD(0, 0);
  for (int it = 0; it < NIT; ++it) {
    const int cur = it & 1;
    u16* Ab = As + cur * TSZ;
    u16* Bb = Bs + cur * TSZ;
    if (A_FP32) {
      bf8u t0, t1;
#pragma unroll
      for (int e = 0; e < 4; ++e) {
        t0.e[e] = f2bf(xa[cur][0].f[e]); t0.e[e + 4] = f2bf(xa[cur][1].f[e]);
        t1.e[e] = f2bf(xa[cur][2].f[e]); t1.e[e + 4] = f2bf(xa[cur][3].f[e]);
      }
      *(frag16*)(&Ab[r * GP + c16])     = t0.v;
      *(frag16*)(&Ab[r * GP + c16 + 8]) = t1.v;
    } else {
      *(frag16*)(&Ab[r * GP + c16])     = ra[cur][0];
      *(frag16*)(&Ab[r * GP + c16 + 8]) = ra[cur][1];
    }
    *(frag16*)(&Bb[r * GP + c16])     = rb[cur][0];
    *(frag16*)(&Bb[r * GP + c16 + 8]) = rb[cur][1];
    if (it + 1 < NIT) LOAD(cur ^ 1, (it + 1) << 6);
    __syncthreads();
#pragma unroll
    for (int ks = 0; ks < 2; ++ks) {
      frag16 af[2], bf[2];
#pragma unroll
      for (int i = 0; i < 2; ++i)
        af[i] = *(const frag16*)(&Ab[(wy * 32 + i * 16 + l15) * GP + ks * 32 + quad * 8]);
#pragma unroll
      for (int j = 0; j < 2; ++j)
        bf[j] = *(const frag16*)(&Bb[(wx * 32 + j * 16 + l15) * GP + ks * 32 + quad * 8]);
#pragma unroll
      for (int i = 0; i < 2; ++i)
#pragma unroll
        for (int j = 0; j < 2; ++j)
          acc[i][j] = __builtin_amdgcn_mfma_f32_16x16x32_bf16(af[i], bf[j], acc[i][j], 0, 0, 0);
    }
  }

  float bj[2];
#pragma unroll
  for (int j = 0; j < 2; ++j)
    bj[j] = bias[col0 + wx * 32 + j * 16 + l15];

#pragma unroll
  for (int i = 0; i < 2; ++i) {
#pragma unroll
    for (int rr = 0; rr < 4; ++rr) {
      const size_t row = row0 + wy * 32 + i * 16 + quad * 4 + rr;
#pragma unroll
      for (int j = 0; j < 2; ++j) {
        const float v = acc[i][j][rr] + bj[j];
        const int col = col0 + wx * 32 + j * 16 + l15;
        if (out_mode == 0)      ((float*)Cout)[row * N + col] = v;
        else if (out_mode == 1) ((u16*)Cout)[row * N + col] = f2bf(v);
        else                    ((u16*)Cout)[(size_t)col * ldT + row] = f2bf(v);
      }
    }
  }
}

__global__ __launch_bounds__(256, 4)
void proj(const float* __restrict__ query, const float* __restrict__ key,
          const float* __restrict__ value,
          const u16* __restrict__ wq_t, const u16* __restrict__ wk_t,
          const u16* __restrict__ wv_t,
          const float* __restrict__ bq, const float* __restrict__ bk,
          const float* __restrict__ bv,
          u16* __restrict__ q_bf, u16* __restrict__ k_bf,
          u16* __restrict__ vt_bf, int M, int K) {
  __shared__ __align__(16) u16 As[2 * TSZ];
  __shared__ __align__(16) u16 Bs[2 * TSZ];
  const int bid = blockIdx.x;
  if (bid < 64)
    gemm64<true>(key, nullptr, wk_t, bk, k_bf, 1, bid * 64, 0, 64, K, 0, As, Bs);
  else if (bid < 128)
    gemm64<true>(value, nullptr, wv_t, bv, vt_bf, 2, (bid - 64) * 64, 0, 64, K, M, As, Bs);
  else {
    const int q = bid - 128;
    gemm64<true>(query, nullptr, wq_t, bq, q_bf, 1, (q >> 4) * 64, (q & 15) * 64, 1024, K, 0, As, Bs);
  }
}

__global__ __launch_bounds__(256, 4)
void out_proj(const u16* __restrict__ ao, const u16* __restrict__ wo_t,
              const float* __restrict__ bo, float* __restrict__ out,
              int M, int K) {
  __shared__ __align__(16) u16 As[2 * TSZ];
  __shared__ __align__(16) u16 Bs[2 * TSZ];
  gemm64<false>(nullptr, ao, wo_t, bo, out, 0,
                blockIdx.y * 64, blockIdx.x * 64, 1024, K, 0, As, Bs);
}

// ---------------------------------------------------------------------------
// Flash MQA attention v2 (unchanged from Round 8, verified):
// mfma_f32_32x32x16_bf16, S^T = K.Q^T trick, no-running-max softmax.
// ---------------------------------------------------------------------------
#define APITCH 72

__global__ __launch_bounds__(256)
void mqa_flash_mfma(const u16* __restrict__ Qb,  // [B,S,1024] bf16
                    const u16* __restrict__ Kb,  // [B,S,64]   bf16
                    const u16* __restrict__ Vt,  // [64][B*S]  bf16 (transposed)
                    u16* __restrict__ O) {       // [B,S,1024] bf16
  const int S = 2048, HID = 1024, D = 64, BS = 4096;
  __shared__ u16 Ks[64 * APITCH];   // K[key][d]
  __shared__ u16 Vs[64 * APITCH];   // V^T[d][key]
  __shared__ u16 Ps[64 * APITCH];   // P[q][key]
  __shared__ float red[2][64];      // per-key-half l partials

  const int tid  = threadIdx.x;
  const int lane = tid & 63;
  const int w    = tid >> 6;
  const int l31  = lane & 31;
  const int hh   = lane >> 5;
  const int kh   = w & 1;
  const int qh   = w >> 1;
  const int qb = blockIdx.x, h = blockIdx.y, b = blockIdx.z;
  const float C2 = 0.04508422002778f;  // log2(e)/32

  const u16* qrow = Qb + (size_t)(b * S + qb * 64 + qh * 32 + l31) * HID + h * D;
  frag16 qf[4];
#pragma unroll
  for (int ks = 0; ks < 4; ++ks)
    qf[ks] = *(const frag16*)(qrow + ks * 16 + hh * 8);

  f32x16 o_acc;
#pragma unroll
  for (int r = 0; r < 16; ++r) o_acc[r] = 0.f;
  float l_lane = 0.f;

  for (int kc = 0; kc < S; kc += 64) {
    __syncthreads();
    {
      const u16* ksrc = Kb + (size_t)(b * S + kc) * D;
      const u16* vsrc = Vt + (size_t)(b * S + kc);
#pragma unroll
      for (int i = 0; i < 2; ++i) {
        const int c = tid + i * 256;
        const int r = c >> 3, col = (c & 7) * 8;
        *(frag16*)(&Ks[r * APITCH + col]) = *(const frag16*)(ksrc + r * D + col);
        *(frag16*)(&Vs[r * APITCH + col]) = *(const frag16*)(vsrc + (size_t)r * BS + col);
      }
    }
    __syncthreads();

    f32x16 sa;
#pragma unroll
    for (int r = 0; r < 16; ++r) sa[r] = 0.f;
#pragma unroll
    for (int ks = 0; ks < 4; ++ks) {
      const frag16 kf = *(const frag16*)(&Ks[(kh * 32 + l31) * APITCH + ks * 16 + hh * 8]);
      sa = __builtin_amdgcn_mfma_f32_32x32x16_bf16(kf, qf[ks], sa, 0, 0, 0);
    }

    const int qrow_l = qh * 32 + l31;
#pragma unroll
    for (int g = 0; g < 4; ++g) {
      float p0 = exp2f(sa[g * 4 + 0] * C2);
      float p1 = exp2f(sa[g * 4 + 1] * C2);
      float p2 = exp2f(sa[g * 4 + 2] * C2);
      float p3 = exp2f(sa[g * 4 + 3] * C2);
      l_lane += p0 + p1 + p2 + p3;
      ushort4 pk;
      pk.x = f2bf(p0); pk.y = f2bf(p1); pk.z = f2bf(p2); pk.w = f2bf(p3);
      *(ushort4*)(&Ps[qrow_l * APITCH + kh * 32 + g * 8 + hh * 4]) = pk;
    }
    __syncthreads();

#pragma unroll
    for (int ks = 0; ks < 4; ++ks) {
      const frag16 pf = *(const frag16*)(&Ps[(qh * 32 + l31) * APITCH + ks * 16 + hh * 8]);
      const frag16 vf = *(const frag16*)(&Vs[(kh * 32 + l31) * APITCH + ks * 16 + hh * 8]);
      o_acc = __builtin_amdgcn_mfma_f32_32x32x16_bf16(pf, vf, o_acc, 0, 0, 0);
    }
  }

  l_lane += __shfl_xor(l_lane, 32);
  __syncthreads();
  if (lane < 32) red[kh][qh * 32 + l31] = l_lane;
  __syncthreads();

#pragma unroll
  for (int r = 0; r < 16; ++r) {
    const int q_local = qh * 32 + (r & 3) + 8 * (r >> 2) + 4 * hh;
    const float li = 1.f / (red[0][q_local] + red[1][q_local]);
    u16* orow = O + (size_t)(b * S + qb * 64 + q_local) * HID + h * D;
    orow[kh * 32 + l31] = f2bf(o_acc[r] * li);
  }
}

extern "C" void kernel_launch(void* const* d_in, const int* in_sizes, int n_in,
                              void* d_out, int out_size, void* d_ws, size_t ws_size,
                              hipStream_t stream) {
  const float* query = (const float*)d_in[0];
  const float* key   = (const float*)d_in[1];
  const float* value = (const float*)d_in[2];
  const float* Wq    = (const float*)d_in[3];
  const float* bq    = (const float*)d_in[4];
  const float* Wk    = (const float*)d_in[5];
  const float* bk    = (const float*)d_in[6];
  const float* Wv    = (const float*)d_in[7];
  const float* bv    = (const float*)d_in[8];
  const float* Wo    = (const float*)d_in[9];
  const float* bo    = (const float*)d_in[10];
  float* out = (float*)d_out;

  const int B = 2, S = 2048, IN = 1024, HID = 1024, H = 16, D = 64;
  const int M = B * S;  // 4096
  const size_t MB = 1024 * 1024;

  char* ws = (char*)d_ws;
  u16* q_bf  = (u16*)ws;                           // [0, 8MB)
  u16* ao_bf = (u16*)(ws + 8 * MB);                // [8, 16MB)
  u16* k_bf  = (u16*)(ws + 16 * MB);               // 0.5 MB
  u16* vt_bf = (u16*)(ws + 16 * MB + 512 * 1024);  // 0.5 MB
  u16* wq_t  = (u16*)(ws + 17 * MB);               // 2 MB [1024][1024]
  u16* wo_t  = (u16*)(ws + 19 * MB);               // 2 MB [1024][1024]
  u16* wk_t  = (u16*)(ws + 21 * MB);               // 128 KB [64][1024]
  u16* wv_t  = (u16*)(ws + 21 * MB + 128 * 1024);  // 128 KB [64][1024]

  dim3 blk(256);
  prep_w<<<dim3(544), blk, 0, stream>>>(Wq, Wo, Wk, Wv, wq_t, wo_t, wk_t, wv_t);
  proj<<<dim3(1152), blk, 0, stream>>>(query, key, value, wq_t, wk_t, wv_t,
                                       bq, bk, bv, q_bf, k_bf, vt_bf, M, IN);
  mqa_flash_mfma<<<dim3(S / 64, H, B), blk, 0, stream>>>(q_bf, k_bf, vt_bf, ao_bf);
  out_proj<<<dim3(HID / 64, M / 64), blk, 0, stream>>>(ao_bf, wo_t, bo, out, M, HID);
}

// Round 10
// 256.879 us; speedup vs baseline: 4.4791x; 4.4791x over previous
//
#include <hip/hip_runtime.h>

// ---------------------------------------------------------------------------
// MQA: out = softmax((X Wq)(X Wk)^T / 32)(X Wv) Wo, MQA broadcast K/V.
// B=2, S=2048, IN=HID=1024, H=16, D=64.
// Round 10: R9's pipelined gemm64 SPILLED — xa[cur] with runtime cur ->
// scratch (WRITE_SIZE 40MB vs 16MB real, MfmaUtil 0.6%). Same pipeline,
// spill-proof: manual 2x unroll, two NAMED register structs (R0/R1, no
// runtime indexing), alternating LDS buffers, one barrier per K-step.
// Attention (32x32 S^T, R8-verified) unchanged.
// ---------------------------------------------------------------------------

typedef unsigned int   u32;
typedef unsigned short u16;
typedef union { float4 v; float f[4]; } f4u;
typedef __attribute__((ext_vector_type(8)))  short frag16;  // 8 bf16 (4 VGPR)
typedef __attribute__((ext_vector_type(4)))  float f32x4;
typedef __attribute__((ext_vector_type(16))) float f32x16;  // 32x32 MFMA acc
typedef union { frag16 v; u16 e[8]; } bf8u;

static __device__ __forceinline__ u16 f2bf(float x) {
  union { float f; u32 u; } v; v.f = x;
  u32 r = v.u + 0x7fff + ((v.u >> 16) & 1);   // RNE
  return (u16)(r >> 16);
}

// ---------------------------------------------------------------------------
// 64x64 transpose+convert tile (prep_w helper).
// ---------------------------------------------------------------------------
static __device__ void tcvt_tile(const float* __restrict__ src,
                                 u16* __restrict__ dst,
                                 int C, int ldT, int rt, int ct,
                                 float (*t)[65]) {
  const int r0 = rt * 64, c0 = ct * 64;
  const int tr  = threadIdx.x >> 4;
  const int tc4 = (threadIdx.x & 15) * 4;
#pragma unroll
  for (int i = 0; i < 4; ++i) {
    f4u v; v.v = *(const float4*)(src + (size_t)(r0 + tr + i * 16) * C + c0 + tc4);
    t[tr + i * 16][tc4 + 0] = v.f[0];
    t[tr + i * 16][tc4 + 1] = v.f[1];
    t[tr + i * 16][tc4 + 2] = v.f[2];
    t[tr + i * 16][tc4 + 3] = v.f[3];
  }
  __syncthreads();
#pragma unroll
  for (int i = 0; i < 4; ++i) {
    const int oc = tr + i * 16;
    ushort4 o;
    o.x = f2bf(t[tc4 + 0][oc]);
    o.y = f2bf(t[tc4 + 1][oc]);
    o.z = f2bf(t[tc4 + 2][oc]);
    o.w = f2bf(t[tc4 + 3][oc]);
    *(ushort4*)(dst + (size_t)(c0 + oc) * ldT + r0 + tc4) = o;
  }
}

__global__ __launch_bounds__(256)
void prep_w(const float* __restrict__ Wq, const float* __restrict__ Wo,
            const float* __restrict__ Wk, const float* __restrict__ Wv,
            u16* __restrict__ wq_t, u16* __restrict__ wo_t,
            u16* __restrict__ wk_t, u16* __restrict__ wv_t) {
  __shared__ float t[64][65];
  const int bid = blockIdx.x;
  if (bid < 256)      tcvt_tile(Wq, wq_t, 1024, 1024, bid >> 4, bid & 15, t);
  else if (bid < 512) tcvt_tile(Wo, wo_t, 1024, 1024, (bid - 256) >> 4, (bid - 256) & 15, t);
  else if (bid < 528) tcvt_tile(Wk, wk_t, 64, 1024, bid - 512, 0, t);
  else                tcvt_tile(Wv, wv_t, 64, 1024, bid - 528, 0, t);
}

// ---------------------------------------------------------------------------
// 64x64-tile bf16 MFMA GEMM — pipelined, spill-proof (no runtime-indexed
// register arrays). BK=64, NIT=K/64 (must be even). Double LDS buffer,
// one barrier per K-step:
//   step it (buf0): store R0, load R1(it+1), sync, MFMA buf0
//   step it+1 (buf1): store R1, load R0(it+2), sync, MFMA buf1
// ---------------------------------------------------------------------------
#define GP 72
#define TSZ (64 * GP)

struct PipeRegs {
  f4u    x0, x1, x2, x3;   // fp32-A path
  frag16 a0, a1;           // bf16-A path
  frag16 b0, b1;           // B
};

template <bool A_FP32>
static __device__ void gemm64(const float* __restrict__ Af32,
                              const u16* __restrict__ Abf,
                              const u16* __restrict__ Bt,
                              const float* __restrict__ bias,
                              void* __restrict__ Cout, int out_mode,
                              int row0, int col0, int N, int K, int ldT,
                              u16* As, u16* Bs) {   // each [2*TSZ]
  const int tid  = threadIdx.x;
  const int lane = tid & 63;
  const int quad = lane >> 4, l15 = lane & 15;
  const int w = tid >> 6, wy = w >> 1, wx = w & 1;

  f32x4 acc[2][2];
#pragma unroll
  for (int i = 0; i < 2; ++i)
#pragma unroll
    for (int j = 0; j < 2; ++j) {
      acc[i][j][0] = 0.f; acc[i][j][1] = 0.f;
      acc[i][j][2] = 0.f; acc[i][j][3] = 0.f;
    }

  const int r = tid >> 2, c16 = (tid & 3) * 16;
  const float* apf = A_FP32 ? (Af32 + (size_t)(row0 + r) * K + c16) : nullptr;
  const u16*   apb = A_FP32 ? nullptr : (Abf + (size_t)(row0 + r) * K + c16);
  const u16*   bp  = Bt + (size_t)(col0 + r) * K + c16;

  PipeRegs R0, R1;

  auto LOAD = [&](PipeRegs& R, int k0) {
    if (A_FP32) {
      R.x0.v = *(const float4*)(apf + k0);
      R.x1.v = *(const float4*)(apf + k0 + 4);
      R.x2.v = *(const float4*)(apf + k0 + 8);
      R.x3.v = *(const float4*)(apf + k0 + 12);
    } else {
      R.a0 = *(const frag16*)(apb + k0);
      R.a1 = *(const frag16*)(apb + k0 + 8);
    }
    R.b0 = *(const frag16*)(bp + k0);
    R.b1 = *(const frag16*)(bp + k0 + 8);
  };

  auto STORE = [&](PipeRegs& R, u16* Ab, u16* Bb) {
    if (A_FP32) {
      bf8u t0, t1;
#pragma unroll
      for (int e = 0; e < 4; ++e) {
        t0.e[e] = f2bf(R.x0.f[e]); t0.e[e + 4] = f2bf(R.x1.f[e]);
        t1.e[e] = f2bf(R.x2.f[e]); t1.e[e + 4] = f2bf(R.x3.f[e]);
      }
      *(frag16*)(&Ab[r * GP + c16])     = t0.v;
      *(frag16*)(&Ab[r * GP + c16 + 8]) = t1.v;
    } else {
      *(frag16*)(&Ab[r * GP + c16])     = R.a0;
      *(frag16*)(&Ab[r * GP + c16 + 8]) = R.a1;
    }
    *(frag16*)(&Bb[r * GP + c16])     = R.b0;
    *(frag16*)(&Bb[r * GP + c16 + 8]) = R.b1;
  };

  auto MFMA = [&](const u16* Ab, const u16* Bb) {
#pragma unroll
    for (int ks = 0; ks < 2; ++ks) {
      frag16 af[2], bf[2];
#pragma unroll
      for (int i = 0; i < 2; ++i)
        af[i] = *(const frag16*)(&Ab[(wy * 32 + i * 16 + l15) * GP + ks * 32 + quad * 8]);
#pragma unroll
      for (int j = 0; j < 2; ++j)
        bf[j] = *(const frag16*)(&Bb[(wx * 32 + j * 16 + l15) * GP + ks * 32 + quad * 8]);
#pragma unroll
      for (int i = 0; i < 2; ++i)
#pragma unroll
        for (int j = 0; j < 2; ++j)
          acc[i][j] = __builtin_amdgcn_mfma_f32_16x16x32_bf16(af[i], bf[j], acc[i][j], 0, 0, 0);
    }
  };

  const int NIT = K >> 6;   // even (K % 128 == 0)
  LOAD(R0, 0);
  for (int it = 0; it < NIT; it += 2) {
    STORE(R0, As, Bs);
    if (it + 1 < NIT) LOAD(R1, (it + 1) << 6);
    __syncthreads();
    MFMA(As, Bs);
    STORE(R1, As + TSZ, Bs + TSZ);
    if (it + 2 < NIT) LOAD(R0, (it + 2) << 6);
    __syncthreads();
    MFMA(As + TSZ, Bs + TSZ);
  }

  float bj[2];
#pragma unroll
  for (int j = 0; j < 2; ++j)
    bj[j] = bias[col0 + wx * 32 + j * 16 + l15];

#pragma unroll
  for (int i = 0; i < 2; ++i) {
#pragma unroll
    for (int rr = 0; rr < 4; ++rr) {
      const size_t row = row0 + wy * 32 + i * 16 + quad * 4 + rr;
#pragma unroll
      for (int j = 0; j < 2; ++j) {
        const float v = acc[i][j][rr] + bj[j];
        const int col = col0 + wx * 32 + j * 16 + l15;
        if (out_mode == 0)      ((float*)Cout)[row * N + col] = v;
        else if (out_mode == 1) ((u16*)Cout)[row * N + col] = f2bf(v);
        else                    ((u16*)Cout)[(size_t)col * ldT + row] = f2bf(v);
      }
    }
  }
}

__global__ __launch_bounds__(256, 4)
void proj(const float* __restrict__ query, const float* __restrict__ key,
          const float* __restrict__ value,
          const u16* __restrict__ wq_t, const u16* __restrict__ wk_t,
          const u16* __restrict__ wv_t,
          const float* __restrict__ bq, const float* __restrict__ bk,
          const float* __restrict__ bv,
          u16* __restrict__ q_bf, u16* __restrict__ k_bf,
          u16* __restrict__ vt_bf, int M, int K) {
  __shared__ __align__(16) u16 As[2 * TSZ];
  __shared__ __align__(16) u16 Bs[2 * TSZ];
  const int bid = blockIdx.x;
  if (bid < 64)
    gemm64<true>(key, nullptr, wk_t, bk, k_bf, 1, bid * 64, 0, 64, K, 0, As, Bs);
  else if (bid < 128)
    gemm64<true>(value, nullptr, wv_t, bv, vt_bf, 2, (bid - 64) * 64, 0, 64, K, M, As, Bs);
  else {
    const int q = bid - 128;
    gemm64<true>(query, nullptr, wq_t, bq, q_bf, 1, (q >> 4) * 64, (q & 15) * 64, 1024, K, 0, As, Bs);
  }
}

__global__ __launch_bounds__(256, 4)
void out_proj(const u16* __restrict__ ao, const u16* __restrict__ wo_t,
              const float* __restrict__ bo, float* __restrict__ out,
              int M, int K) {
  __shared__ __align__(16) u16 As[2 * TSZ];
  __shared__ __align__(16) u16 Bs[2 * TSZ];
  gemm64<false>(nullptr, ao, wo_t, bo, out, 0,
                blockIdx.y * 64, blockIdx.x * 64, 1024, K, 0, As, Bs);
}

// ---------------------------------------------------------------------------
// Flash MQA attention v2 (unchanged from Round 8, verified):
// mfma_f32_32x32x16_bf16, S^T = K.Q^T trick, no-running-max softmax.
// ---------------------------------------------------------------------------
#define APITCH 72

__global__ __launch_bounds__(256)
void mqa_flash_mfma(const u16* __restrict__ Qb,  // [B,S,1024] bf16
                    const u16* __restrict__ Kb,  // [B,S,64]   bf16
                    const u16* __restrict__ Vt,  // [64][B*S]  bf16 (transposed)
                    u16* __restrict__ O) {       // [B,S,1024] bf16
  const int S = 2048, HID = 1024, D = 64, BS = 4096;
  __shared__ u16 Ks[64 * APITCH];   // K[key][d]
  __shared__ u16 Vs[64 * APITCH];   // V^T[d][key]
  __shared__ u16 Ps[64 * APITCH];   // P[q][key]
  __shared__ float red[2][64];      // per-key-half l partials

  const int tid  = threadIdx.x;
  const int lane = tid & 63;
  const int w    = tid >> 6;
  const int l31  = lane & 31;
  const int hh   = lane >> 5;
  const int kh   = w & 1;
  const int qh   = w >> 1;
  const int qb = blockIdx.x, h = blockIdx.y, b = blockIdx.z;
  const float C2 = 0.04508422002778f;  // log2(e)/32

  const u16* qrow = Qb + (size_t)(b * S + qb * 64 + qh * 32 + l31) * HID + h * D;
  frag16 qf[4];
#pragma unroll
  for (int ks = 0; ks < 4; ++ks)
    qf[ks] = *(const frag16*)(qrow + ks * 16 + hh * 8);

  f32x16 o_acc;
#pragma unroll
  for (int r = 0; r < 16; ++r) o_acc[r] = 0.f;
  float l_lane = 0.f;

  for (int kc = 0; kc < S; kc += 64) {
    __syncthreads();
    {
      const u16* ksrc = Kb + (size_t)(b * S + kc) * D;
      const u16* vsrc = Vt + (size_t)(b * S + kc);
#pragma unroll
      for (int i = 0; i < 2; ++i) {
        const int c = tid + i * 256;
        const int r = c >> 3, col = (c & 7) * 8;
        *(frag16*)(&Ks[r * APITCH + col]) = *(const frag16*)(ksrc + r * D + col);
        *(frag16*)(&Vs[r * APITCH + col]) = *(const frag16*)(vsrc + (size_t)r * BS + col);
      }
    }
    __syncthreads();

    f32x16 sa;
#pragma unroll
    for (int r = 0; r < 16; ++r) sa[r] = 0.f;
#pragma unroll
    for (int ks = 0; ks < 4; ++ks) {
      const frag16 kf = *(const frag16*)(&Ks[(kh * 32 + l31) * APITCH + ks * 16 + hh * 8]);
      sa = __builtin_amdgcn_mfma_f32_32x32x16_bf16(kf, qf[ks], sa, 0, 0, 0);
    }

    const int qrow_l = qh * 32 + l31;
#pragma unroll
    for (int g = 0; g < 4; ++g) {
      float p0 = exp2f(sa[g * 4 + 0] * C2);
      float p1 = exp2f(sa[g * 4 + 1] * C2);
      float p2 = exp2f(sa[g * 4 + 2] * C2);
      float p3 = exp2f(sa[g * 4 + 3] * C2);
      l_lane += p0 + p1 + p2 + p3;
      ushort4 pk;
      pk.x = f2bf(p0); pk.y = f2bf(p1); pk.z = f2bf(p2); pk.w = f2bf(p3);
      *(ushort4*)(&Ps[qrow_l * APITCH + kh * 32 + g * 8 + hh * 4]) = pk;
    }
    __syncthreads();

#pragma unroll
    for (int ks = 0; ks < 4; ++ks) {
      const frag16 pf = *(const frag16*)(&Ps[(qh * 32 + l31) * APITCH + ks * 16 + hh * 8]);
      const frag16 vf = *(const frag16*)(&Vs[(kh * 32 + l31) * APITCH + ks * 16 + hh * 8]);
      o_acc = __builtin_amdgcn_mfma_f32_32x32x16_bf16(pf, vf, o_acc, 0, 0, 0);
    }
  }

  l_lane += __shfl_xor(l_lane, 32);
  __syncthreads();
  if (lane < 32) red[kh][qh * 32 + l31] = l_lane;
  __syncthreads();

#pragma unroll
  for (int r = 0; r < 16; ++r) {
    const int q_local = qh * 32 + (r & 3) + 8 * (r >> 2) + 4 * hh;
    const float li = 1.f / (red[0][q_local] + red[1][q_local]);
    u16* orow = O + (size_t)(b * S + qb * 64 + q_local) * HID + h * D;
    orow[kh * 32 + l31] = f2bf(o_acc[r] * li);
  }
}

extern "C" void kernel_launch(void* const* d_in, const int* in_sizes, int n_in,
                              void* d_out, int out_size, void* d_ws, size_t ws_size,
                              hipStream_t stream) {
  const float* query = (const float*)d_in[0];
  const float* key   = (const float*)d_in[1];
  const float* value = (const float*)d_in[2];
  const float* Wq    = (const float*)d_in[3];
  const float* bq    = (const float*)d_in[4];
  const float* Wk    = (const float*)d_in[5];
  const float* bk    = (const float*)d_in[6];
  const float* Wv    = (const float*)d_in[7];
  const float* bv    = (const float*)d_in[8];
  const float* Wo    = (const float*)d_in[9];
  const float* bo    = (const float*)d_in[10];
  float* out = (float*)d_out;

  const int B = 2, S = 2048, IN = 1024, HID = 1024, H = 16, D = 64;
  const int M = B * S;  // 4096
  const size_t MB = 1024 * 1024;

  char* ws = (char*)d_ws;
  u16* q_bf  = (u16*)ws;                           // [0, 8MB)
  u16* ao_bf = (u16*)(ws + 8 * MB);                // [8, 16MB)
  u16* k_bf  = (u16*)(ws + 16 * MB);               // 0.5 MB
  u16* vt_bf = (u16*)(ws + 16 * MB + 512 * 1024);  // 0.5 MB
  u16* wq_t  = (u16*)(ws + 17 * MB);               // 2 MB [1024][1024]
  u16* wo_t  = (u16*)(ws + 19 * MB);               // 2 MB [1024][1024]
  u16* wk_t  = (u16*)(ws + 21 * MB);               // 128 KB [64][1024]
  u16* wv_t  = (u16*)(ws + 21 * MB + 128 * 1024);  // 128 KB [64][1024]

  dim3 blk(256);
  prep_w<<<dim3(544), blk, 0, stream>>>(Wq, Wo, Wk, Wv, wq_t, wo_t, wk_t, wv_t);
  proj<<<dim3(1152), blk, 0, stream>>>(query, key, value, wq_t, wk_t, wv_t,
                                       bq, bk, bv, q_bf, k_bf, vt_bf, M, IN);
  mqa_flash_mfma<<<dim3(S / 64, H, B), blk, 0, stream>>>(q_bf, k_bf, vt_bf, ao_bf);
  out_proj<<<dim3(HID / 64, M / 64), blk, 0, stream>>>(ao_bf, wo_t, bo, out, M, HID);
}